// Round 1
// baseline (188.302 us; speedup 1.0000x reference)
//
#include <hip/hip_runtime.h>
#include <math.h>

#define HGT 224
#define WID 224
#define NPIX (HGT * WID)
#define SIGMA 0.0003f
#define EPSV 1e-10f
#define FSTRIDE 36   // floats per face record

// Face record layout (floats):
//  0-5 : x0,y0,x1,y1,x2,y2           (projected 2D verts)
//  6-9 : a00,a01,a10,a11             (barycentric coeffs, pre-divided by denom)
// 10-12: z0,z1,z2                    (camera-space z per vertex)
// 13   : front flag (1.0 / 0.0)
// 14-22: c0r,c0g,c0b, c1r,c1g,c1b, c2r,c2g,c2b
// 23   : pad
// 24-26: e01x,e01y,inv01             (segment 0->1: edge vec + 1/(|e|^2+eps))
// 27-29: e12x,e12y,inv12
// 30-32: e20x,e20y,inv20
// 33-35: pad

__global__ void face_pre(const float* __restrict__ points,
                         const int* __restrict__ faces,
                         const float* __restrict__ rot,
                         const float* __restrict__ pos,
                         const float* __restrict__ proj,
                         const float* __restrict__ colors,
                         float* __restrict__ fd,
                         float* __restrict__ out_normal,
                         int B, int P, int F) {
    int gid = blockIdx.x * blockDim.x + threadIdx.x;
    if (gid >= B * F) return;
    int b = gid / F;
    int f = gid - b * F;

    const float* Rb = rot + b * 9;
    float posx = pos[b * 3 + 0], posy = pos[b * 3 + 1], posz = pos[b * 3 + 2];
    float pj0 = proj[0], pj1 = proj[1], pj2 = proj[2];

    float pcx[3], pcy[3], pcz[3], qx[3], qy[3], col[9];
    for (int v = 0; v < 3; v++) {
        int i = faces[f * 3 + v];
        float dx = points[(b * P + i) * 3 + 0] - posx;
        float dy = points[(b * P + i) * 3 + 1] - posy;
        float dz = points[(b * P + i) * 3 + 2] - posz;
        // pc[i] = sum_j d[j] * rot[i][j]
        pcx[v] = Rb[0] * dx + Rb[1] * dy + Rb[2] * dz;
        pcy[v] = Rb[3] * dx + Rb[4] * dy + Rb[5] * dz;
        pcz[v] = Rb[6] * dx + Rb[7] * dy + Rb[8] * dz;
        float zz = pcz[v] * pj2;
        qx[v] = (pcx[v] * pj0) / zz;
        qy[v] = (pcy[v] * pj1) / zz;
        col[v * 3 + 0] = colors[(b * P + i) * 3 + 0];
        col[v * 3 + 1] = colors[(b * P + i) * 3 + 1];
        col[v * 3 + 2] = colors[(b * P + i) * 3 + 2];
    }

    // normal = cross(p1-p0, p2-p0), normalized copy to output
    float ux = pcx[1] - pcx[0], uy = pcy[1] - pcy[0], uz = pcz[1] - pcz[0];
    float vx = pcx[2] - pcx[0], vy = pcy[2] - pcy[0], vz = pcz[2] - pcz[0];
    float nx = uy * vz - uz * vy;
    float ny = uz * vx - ux * vz;
    float nz = ux * vy - uy * vx;
    float ninv = 1.0f / sqrtf(nx * nx + ny * ny + nz * nz + EPSV);
    out_normal[gid * 3 + 0] = nx * ninv;
    out_normal[gid * 3 + 1] = ny * ninv;
    out_normal[gid * 3 + 2] = nz * ninv;

    float x0 = qx[0], y0 = qy[0], x1 = qx[1], y1 = qy[1], x2 = qx[2], y2 = qy[2];
    float denom = (y1 - y2) * (x0 - x2) + (x2 - x1) * (y0 - y2);
    if (fabsf(denom) < EPSV) denom = EPSV;
    float rd = 1.0f / denom;

    float* fp = fd + gid * FSTRIDE;
    fp[0] = x0; fp[1] = y0; fp[2] = x1; fp[3] = y1; fp[4] = x2; fp[5] = y2;
    fp[6] = (y1 - y2) * rd;
    fp[7] = (x2 - x1) * rd;
    fp[8] = (y2 - y0) * rd;
    fp[9] = (x0 - x2) * rd;
    fp[10] = pcz[0]; fp[11] = pcz[1]; fp[12] = pcz[2];
    fp[13] = (nz > 0.0f) ? 1.0f : 0.0f;
    for (int k = 0; k < 9; k++) fp[14 + k] = col[k];
    fp[23] = 0.0f;

    float e01x = x1 - x0, e01y = y1 - y0;
    float e12x = x2 - x1, e12y = y2 - y1;
    float e20x = x0 - x2, e20y = y0 - y2;
    fp[24] = e01x; fp[25] = e01y; fp[26] = 1.0f / (e01x * e01x + e01y * e01y + EPSV);
    fp[27] = e12x; fp[28] = e12y; fp[29] = 1.0f / (e12x * e12x + e12y * e12y + EPSV);
    fp[30] = e20x; fp[31] = e20y; fp[32] = 1.0f / (e20x * e20x + e20y * e20y + EPSV);
    fp[33] = 0.0f; fp[34] = 0.0f; fp[35] = 0.0f;
}

__device__ __forceinline__ float seg_d2(float px, float py, float ax, float ay,
                                        float ex, float ey, float inv) {
    float pax = px - ax, pay = py - ay;
    float t = (pax * ex + pay * ey) * inv;
    t = fminf(fmaxf(t, 0.0f), 1.0f);
    float ddx = pax - t * ex;
    float ddy = pay - t * ey;
    return ddx * ddx + ddy * ddy;
}

__global__ __launch_bounds__(64) void rast(const float* __restrict__ fd,
                                           float* __restrict__ out,
                                           int B, int F) {
    const int blocks_per_batch = NPIX / 64; // 784
    int b = blockIdx.x / blocks_per_batch;
    int pix = (blockIdx.x - b * blocks_per_batch) * 64 + threadIdx.x;
    int y = pix / WID;
    int x = pix - y * WID;
    float px = (2.0f * (float)x + 1.0f) / (float)WID - 1.0f;
    float py = 1.0f - (2.0f * (float)y + 1.0f) / (float)HGT;

    const float* fb = fd + b * F * FSTRIDE;

    float best = -1e10f;
    int bidx = 0;
    float bl0 = 0.0f, bl1 = 0.0f, bl2 = 0.0f;
    bool found = false;
    float s = 0.0f;

    for (int f = 0; f < F; f++) {
        const float* fp = fb + f * FSTRIDE;
        float x0 = fp[0], y0 = fp[1], x1 = fp[2], y1 = fp[3], x2 = fp[4], y2 = fp[5];
        float a00 = fp[6], a01 = fp[7], a10 = fp[8], a11 = fp[9];
        float z0 = fp[10], z1 = fp[11], z2 = fp[12];
        bool isfront = fp[13] > 0.0f;

        float dx2 = px - x2, dy2 = py - y2;
        float lam0 = a00 * dx2 + a01 * dy2;
        float lam1 = a10 * dx2 + a11 * dy2;
        float lam2 = 1.0f - lam0 - lam1;
        bool inside = (lam0 >= 0.0f) && (lam1 >= 0.0f) && (lam2 >= 0.0f);
        float zpix = lam0 * z0 + lam1 * z1 + lam2 * z2;

        bool valid = inside && isfront;
        float score = valid ? zpix : -1e10f;
        if (score > best) {
            best = score; bidx = f;
            bl0 = lam0; bl1 = lam1; bl2 = lam2;
            found = true;
        }

        if (isfront) {
            float d2;
            if (inside) {
                d2 = 0.0f;
            } else {
                float dA = seg_d2(px, py, x0, y0, fp[24], fp[25], fp[26]);
                float dB = seg_d2(px, py, x1, y1, fp[27], fp[28], fp[29]);
                float dC = seg_d2(px, py, x2, y2, fp[30], fp[31], fp[32]);
                d2 = fminf(dA, fminf(dB, dC));
            }
            float arg = d2 * (-1.0f / SIGMA);
            if (arg > -87.0f) {
                float pr = expf(arg) * (1.0f - 1e-7f);
                s += log1pf(-pr);
            }
        }
    }

    float r = 0.0f, g = 0.0f, bb = 0.0f;
    if (found) {
        const float* fp = fb + bidx * FSTRIDE;
        r  = bl0 * fp[14] + bl1 * fp[17] + bl2 * fp[20];
        g  = bl0 * fp[15] + bl1 * fp[18] + bl2 * fp[21];
        bb = bl0 * fp[16] + bl1 * fp[19] + bl2 * fp[22];
    }

    int pixidx = b * NPIX + pix;
    out[pixidx * 3 + 0] = r;
    out[pixidx * 3 + 1] = g;
    out[pixidx * 3 + 2] = bb;
    // improb region starts after B*NPIX*3
    out[B * NPIX * 3 + pixidx] = 1.0f - expf(s);
}

extern "C" void kernel_launch(void* const* d_in, const int* in_sizes, int n_in,
                              void* d_out, int out_size, void* d_ws, size_t ws_size,
                              hipStream_t stream) {
    const float* points = (const float*)d_in[0];
    const int*   faces  = (const int*)d_in[1];
    const float* rot    = (const float*)d_in[2];
    const float* pos    = (const float*)d_in[3];
    const float* proj   = (const float*)d_in[4];
    const float* colors = (const float*)d_in[5];
    float* out = (float*)d_out;

    int F = in_sizes[1] / 3;          // 256
    int B = in_sizes[3] / 3;          // 2
    int P = in_sizes[0] / (3 * B);    // 2048

    float* fd = (float*)d_ws;                      // B*F*FSTRIDE floats
    float* out_normal = out + B * NPIX * 3 + B * NPIX; // normal1 slice

    int nf = B * F;
    face_pre<<<(nf + 255) / 256, 256, 0, stream>>>(points, faces, rot, pos, proj,
                                                   colors, fd, out_normal, B, P, F);

    int blocks = B * (NPIX / 64);
    rast<<<blocks, 64, 0, stream>>>(fd, out, B, F);
}

// Round 2
// 115.017 us; speedup vs baseline: 1.6372x; 1.6372x over previous
//
#include <hip/hip_runtime.h>
#include <math.h>

#define HGT 224
#define WID 224
#define NPIX (HGT * WID)
#define SIGMA 0.0003f
#define EPSV 1e-10f
#define FSTRIDE 36   // floats per face record
// d2 cutoff: exp(-d2/SIGMA) < 1e-38 when d2 > 87.5*SIGMA
#define D2_CUT (88.0f * SIGMA)

// Face record layout (floats):
//  0-5 : x0,y0,x1,y1,x2,y2           (projected 2D verts)
//  6-9 : a00,a01,a10,a11             (barycentric coeffs, pre-divided by denom)
// 10-12: z0,z1,z2                    (camera-space z per vertex)
// 13   : front flag (1.0 / 0.0)
// 14-22: c0r,c0g,c0b, c1r,c1g,c1b, c2r,c2g,c2b
// 23   : bbox x min
// 24-26: e01x,e01y,inv01             (segment 0->1: edge vec + 1/(|e|^2+eps))
// 27-29: e12x,e12y,inv12
// 30-32: e20x,e20y,inv20
// 33-35: bbox y min, bbox x max, bbox y max

__global__ void face_pre(const float* __restrict__ points,
                         const int* __restrict__ faces,
                         const float* __restrict__ rot,
                         const float* __restrict__ pos,
                         const float* __restrict__ proj,
                         const float* __restrict__ colors,
                         float* __restrict__ fd,
                         float* __restrict__ out_normal,
                         int B, int P, int F) {
    int gid = blockIdx.x * blockDim.x + threadIdx.x;
    if (gid >= B * F) return;
    int b = gid / F;
    int f = gid - b * F;

    const float* Rb = rot + b * 9;
    float posx = pos[b * 3 + 0], posy = pos[b * 3 + 1], posz = pos[b * 3 + 2];
    float pj0 = proj[0], pj1 = proj[1], pj2 = proj[2];

    float pcx[3], pcy[3], pcz[3], qx[3], qy[3], col[9];
    for (int v = 0; v < 3; v++) {
        int i = faces[f * 3 + v];
        float dx = points[(b * P + i) * 3 + 0] - posx;
        float dy = points[(b * P + i) * 3 + 1] - posy;
        float dz = points[(b * P + i) * 3 + 2] - posz;
        pcx[v] = Rb[0] * dx + Rb[1] * dy + Rb[2] * dz;
        pcy[v] = Rb[3] * dx + Rb[4] * dy + Rb[5] * dz;
        pcz[v] = Rb[6] * dx + Rb[7] * dy + Rb[8] * dz;
        float zz = pcz[v] * pj2;
        qx[v] = (pcx[v] * pj0) / zz;
        qy[v] = (pcy[v] * pj1) / zz;
        col[v * 3 + 0] = colors[(b * P + i) * 3 + 0];
        col[v * 3 + 1] = colors[(b * P + i) * 3 + 1];
        col[v * 3 + 2] = colors[(b * P + i) * 3 + 2];
    }

    float ux = pcx[1] - pcx[0], uy = pcy[1] - pcy[0], uz = pcz[1] - pcz[0];
    float vx = pcx[2] - pcx[0], vy = pcy[2] - pcy[0], vz = pcz[2] - pcz[0];
    float nx = uy * vz - uz * vy;
    float ny = uz * vx - ux * vz;
    float nz = ux * vy - uy * vx;
    float ninv = 1.0f / sqrtf(nx * nx + ny * ny + nz * nz + EPSV);
    out_normal[gid * 3 + 0] = nx * ninv;
    out_normal[gid * 3 + 1] = ny * ninv;
    out_normal[gid * 3 + 2] = nz * ninv;

    float x0 = qx[0], y0 = qy[0], x1 = qx[1], y1 = qy[1], x2 = qx[2], y2 = qy[2];
    float denom = (y1 - y2) * (x0 - x2) + (x2 - x1) * (y0 - y2);
    if (fabsf(denom) < EPSV) denom = EPSV;
    float rd = 1.0f / denom;

    float* fp = fd + gid * FSTRIDE;
    fp[0] = x0; fp[1] = y0; fp[2] = x1; fp[3] = y1; fp[4] = x2; fp[5] = y2;
    fp[6] = (y1 - y2) * rd;
    fp[7] = (x2 - x1) * rd;
    fp[8] = (y2 - y0) * rd;
    fp[9] = (x0 - x2) * rd;
    fp[10] = pcz[0]; fp[11] = pcz[1]; fp[12] = pcz[2];
    fp[13] = (nz > 0.0f) ? 1.0f : 0.0f;
    for (int k = 0; k < 9; k++) fp[14 + k] = col[k];

    float e01x = x1 - x0, e01y = y1 - y0;
    float e12x = x2 - x1, e12y = y2 - y1;
    float e20x = x0 - x2, e20y = y0 - y2;
    fp[24] = e01x; fp[25] = e01y; fp[26] = 1.0f / (e01x * e01x + e01y * e01y + EPSV);
    fp[27] = e12x; fp[28] = e12y; fp[29] = 1.0f / (e12x * e12x + e12y * e12y + EPSV);
    fp[30] = e20x; fp[31] = e20y; fp[32] = 1.0f / (e20x * e20x + e20y * e20y + EPSV);

    // bbox for early-out
    fp[23] = fminf(x0, fminf(x1, x2));
    fp[33] = fminf(y0, fminf(y1, y2));
    fp[34] = fmaxf(x0, fmaxf(x1, x2));
    fp[35] = fmaxf(y0, fmaxf(y1, y2));
}

__device__ __forceinline__ float seg_d2(float px, float py, float ax, float ay,
                                        float ex, float ey, float inv) {
    float pax = px - ax, pay = py - ay;
    float t = (pax * ex + pay * ey) * inv;
    t = fminf(fmaxf(t, 0.0f), 1.0f);
    float ddx = pax - t * ex;
    float ddy = pay - t * ey;
    return ddx * ddx + ddy * ddy;
}

// 256 threads = 4 waves. Each block covers 64 pixels; wave w handles face
// chunk [w*F/4, (w+1)*F/4). Argmax-z + log1p-sum combined via LDS.
__global__ __launch_bounds__(256) void rast(const float* __restrict__ fd,
                                            float* __restrict__ out,
                                            int B, int F) {
    const int blocks_per_batch = NPIX / 64; // 784
    int b = blockIdx.x / blocks_per_batch;
    int t = threadIdx.x & 63;
    int w = threadIdx.x >> 6;
    int pix = (blockIdx.x - b * blocks_per_batch) * 64 + t;
    int y = pix / WID;
    int x = pix - y * WID;
    float px = (2.0f * (float)x + 1.0f) / (float)WID - 1.0f;
    float py = 1.0f - (2.0f * (float)y + 1.0f) / (float)HGT;

    const float* fb = fd + b * F * FSTRIDE;

    int chunk = (F + 3) >> 2;
    int fbeg = w * chunk;
    int fend = min(fbeg + chunk, F);

    float best = -1e10f;
    int bidx = -1;
    float bl0 = 0.0f, bl1 = 0.0f, bl2 = 0.0f;
    float s = 0.0f;

    for (int f = fbeg; f < fend; f++) {
        const float* fp = fb + f * FSTRIDE;
        bool isfront = fp[13] > 0.0f;
        // cheap conservative skip: squared distance to bbox > cutoff ->
        // not inside AND exp(-d2/sigma) < 1e-38 (invisible in the sum)
        float ddx = fmaxf(fmaxf(fp[23] - px, px - fp[34]), 0.0f);
        float ddy = fmaxf(fmaxf(fp[33] - py, py - fp[35]), 0.0f);
        bool near = (ddx * ddx + ddy * ddy) < D2_CUT;

        if (isfront && near) {
            float x0 = fp[0], y0 = fp[1], x1 = fp[2], y1 = fp[3], x2 = fp[4], y2 = fp[5];
            float dx2 = px - x2, dy2 = py - y2;
            float lam0 = fp[6] * dx2 + fp[7] * dy2;
            float lam1 = fp[8] * dx2 + fp[9] * dy2;
            float lam2 = 1.0f - lam0 - lam1;
            bool inside = (lam0 >= 0.0f) && (lam1 >= 0.0f) && (lam2 >= 0.0f);

            if (inside) {
                float zpix = lam0 * fp[10] + lam1 * fp[11] + lam2 * fp[12];
                if (zpix > best) {
                    best = zpix; bidx = f;
                    bl0 = lam0; bl1 = lam1; bl2 = lam2;
                }
                s += log1pf(-(1.0f - 1e-7f));   // d2 = 0 -> pr = 1-1e-7
            } else {
                float dA = seg_d2(px, py, x0, y0, fp[24], fp[25], fp[26]);
                float dB = seg_d2(px, py, x1, y1, fp[27], fp[28], fp[29]);
                float dC = seg_d2(px, py, x2, y2, fp[30], fp[31], fp[32]);
                float d2 = fminf(dA, fminf(dB, dC));
                float arg = d2 * (-1.0f / SIGMA);
                if (arg > -87.0f) {
                    float pr = expf(arg) * (1.0f - 1e-7f);
                    s += log1pf(-pr);
                }
            }
        }
    }

    __shared__ float sc[256], sl0[256], sl1[256], sl2[256], ss[256];
    __shared__ int sidx[256];
    sc[threadIdx.x] = best;
    sl0[threadIdx.x] = bl0; sl1[threadIdx.x] = bl1; sl2[threadIdx.x] = bl2;
    ss[threadIdx.x] = s;
    sidx[threadIdx.x] = bidx;
    __syncthreads();

    if (w == 0) {
        best = -1e10f; bidx = -1;
        bl0 = 0.0f; bl1 = 0.0f; bl2 = 0.0f;
        s = 0.0f;
        for (int k = 0; k < 4; k++) {
            int j = k * 64 + t;
            s += ss[j];
            float v = sc[j];
            if (v > best) {          // ascending chunk order => first-max kept
                best = v; bidx = sidx[j];
                bl0 = sl0[j]; bl1 = sl1[j]; bl2 = sl2[j];
            }
        }

        float r = 0.0f, g = 0.0f, bb = 0.0f;
        if (bidx >= 0) {
            const float* fp = fb + bidx * FSTRIDE;
            r  = bl0 * fp[14] + bl1 * fp[17] + bl2 * fp[20];
            g  = bl0 * fp[15] + bl1 * fp[18] + bl2 * fp[21];
            bb = bl0 * fp[16] + bl1 * fp[19] + bl2 * fp[22];
        }

        int pixidx = b * NPIX + pix;
        out[pixidx * 3 + 0] = r;
        out[pixidx * 3 + 1] = g;
        out[pixidx * 3 + 2] = bb;
        out[B * NPIX * 3 + pixidx] = 1.0f - expf(s);
    }
}

extern "C" void kernel_launch(void* const* d_in, const int* in_sizes, int n_in,
                              void* d_out, int out_size, void* d_ws, size_t ws_size,
                              hipStream_t stream) {
    const float* points = (const float*)d_in[0];
    const int*   faces  = (const int*)d_in[1];
    const float* rot    = (const float*)d_in[2];
    const float* pos    = (const float*)d_in[3];
    const float* proj   = (const float*)d_in[4];
    const float* colors = (const float*)d_in[5];
    float* out = (float*)d_out;

    int F = in_sizes[1] / 3;          // 256
    int B = in_sizes[3] / 3;          // 2
    int P = in_sizes[0] / (3 * B);    // 2048

    float* fd = (float*)d_ws;                          // B*F*FSTRIDE floats
    float* out_normal = out + B * NPIX * 3 + B * NPIX; // normal1 slice

    int nf = B * F;
    face_pre<<<(nf + 255) / 256, 256, 0, stream>>>(points, faces, rot, pos, proj,
                                                   colors, fd, out_normal, B, P, F);

    int blocks = B * (NPIX / 64);
    rast<<<blocks, 256, 0, stream>>>(fd, out, B, F);
}

// Round 3
// 100.606 us; speedup vs baseline: 1.8717x; 1.1432x over previous
//
#include <hip/hip_runtime.h>
#include <math.h>

#define HGT 224
#define WID 224
#define NPIX (HGT * WID)
#define SIGMA 0.0003f
#define EPSV 1e-10f
#define FSTRIDE 36   // floats per face record
// margin: beyond sqrt(88*SIGMA) from the triangle, exp(-d2/SIGMA) < 6e-39
// -> factor (1-pr) rounds to exactly 1.0f; skipping is numerically exact.
#define MARGIN 0.1626f

// Face record layout (floats):
//  0-3 : bxmin, bymin, bxmax, bymax   (backface -> inverted inf bbox = never hit)
//  4-9 : x0,y0,x1,y1,x2,y2            (projected 2D verts)
// 10-13: a00,a01,a10,a11              (barycentric coeffs, pre-divided by denom)
// 14-16: z0,z1,z2                     (camera-space z per vertex)
// 17   : pad
// 18-26: c0r,c0g,c0b, c1r,c1g,c1b, c2r,c2g,c2b
// 27-29: e01x,e01y,inv01              (segment 0->1: edge vec + 1/(|e|^2+eps))
// 30-32: e12x,e12y,inv12
// 33-35: e20x,e20y,inv20

__global__ void face_pre(const float* __restrict__ points,
                         const int* __restrict__ faces,
                         const float* __restrict__ rot,
                         const float* __restrict__ pos,
                         const float* __restrict__ proj,
                         const float* __restrict__ colors,
                         float* __restrict__ fd,
                         float* __restrict__ out_normal,
                         int B, int P, int F) {
    int gid = blockIdx.x * blockDim.x + threadIdx.x;
    if (gid >= B * F) return;
    int b = gid / F;
    int f = gid - b * F;

    const float* Rb = rot + b * 9;
    float posx = pos[b * 3 + 0], posy = pos[b * 3 + 1], posz = pos[b * 3 + 2];
    float pj0 = proj[0], pj1 = proj[1], pj2 = proj[2];

    float pcx[3], pcy[3], pcz[3], qx[3], qy[3], col[9];
    for (int v = 0; v < 3; v++) {
        int i = faces[f * 3 + v];
        float dx = points[(b * P + i) * 3 + 0] - posx;
        float dy = points[(b * P + i) * 3 + 1] - posy;
        float dz = points[(b * P + i) * 3 + 2] - posz;
        pcx[v] = Rb[0] * dx + Rb[1] * dy + Rb[2] * dz;
        pcy[v] = Rb[3] * dx + Rb[4] * dy + Rb[5] * dz;
        pcz[v] = Rb[6] * dx + Rb[7] * dy + Rb[8] * dz;
        float zz = pcz[v] * pj2;
        qx[v] = (pcx[v] * pj0) / zz;
        qy[v] = (pcy[v] * pj1) / zz;
        col[v * 3 + 0] = colors[(b * P + i) * 3 + 0];
        col[v * 3 + 1] = colors[(b * P + i) * 3 + 1];
        col[v * 3 + 2] = colors[(b * P + i) * 3 + 2];
    }

    float ux = pcx[1] - pcx[0], uy = pcy[1] - pcy[0], uz = pcz[1] - pcz[0];
    float vx = pcx[2] - pcx[0], vy = pcy[2] - pcy[0], vz = pcz[2] - pcz[0];
    float nx = uy * vz - uz * vy;
    float ny = uz * vx - ux * vz;
    float nz = ux * vy - uy * vx;
    float ninv = 1.0f / sqrtf(nx * nx + ny * ny + nz * nz + EPSV);
    out_normal[gid * 3 + 0] = nx * ninv;
    out_normal[gid * 3 + 1] = ny * ninv;
    out_normal[gid * 3 + 2] = nz * ninv;

    float x0 = qx[0], y0 = qy[0], x1 = qx[1], y1 = qy[1], x2 = qx[2], y2 = qy[2];
    float denom = (y1 - y2) * (x0 - x2) + (x2 - x1) * (y0 - y2);
    if (fabsf(denom) < EPSV) denom = EPSV;
    float rd = 1.0f / denom;

    float* fp = fd + gid * FSTRIDE;
    bool front = nz > 0.0f;
    // backfaces: inverted bbox at +/-inf -> every tile test fails
    fp[0] = front ? fminf(x0, fminf(x1, x2)) :  1e30f;
    fp[1] = front ? fminf(y0, fminf(y1, y2)) :  1e30f;
    fp[2] = front ? fmaxf(x0, fmaxf(x1, x2)) : -1e30f;
    fp[3] = front ? fmaxf(y0, fmaxf(y1, y2)) : -1e30f;

    fp[4] = x0; fp[5] = y0; fp[6] = x1; fp[7] = y1; fp[8] = x2; fp[9] = y2;
    fp[10] = (y1 - y2) * rd;
    fp[11] = (x2 - x1) * rd;
    fp[12] = (y2 - y0) * rd;
    fp[13] = (x0 - x2) * rd;
    fp[14] = pcz[0]; fp[15] = pcz[1]; fp[16] = pcz[2];
    fp[17] = 0.0f;
    for (int k = 0; k < 9; k++) fp[18 + k] = col[k];

    float e01x = x1 - x0, e01y = y1 - y0;
    float e12x = x2 - x1, e12y = y2 - y1;
    float e20x = x0 - x2, e20y = y0 - y2;
    fp[27] = e01x; fp[28] = e01y; fp[29] = 1.0f / (e01x * e01x + e01y * e01y + EPSV);
    fp[30] = e12x; fp[31] = e12y; fp[32] = 1.0f / (e12x * e12x + e12y * e12y + EPSV);
    fp[33] = e20x; fp[34] = e20y; fp[35] = 1.0f / (e20x * e20x + e20y * e20y + EPSV);
}

__device__ __forceinline__ float seg_d2(float px, float py, float ax, float ay,
                                        float ex, float ey, float inv) {
    float pax = px - ax, pay = py - ay;
    float t = (pax * ex + pay * ey) * inv;
    t = fminf(fmaxf(t, 0.0f), 1.0f);
    float ddx = pax - t * ex;
    float ddy = pay - t * ey;
    return ddx * ddx + ddy * ddy;
}

// 256 threads = 4 waves. Each block covers one 8x8 pixel tile (64 pixels);
// wave w handles face chunk [w*F/4, (w+1)*F/4). The face-vs-tile bbox test
// is wave-uniform -> whole heavy body skipped via scalar branch.
__global__ __launch_bounds__(256) void rast(const float* __restrict__ fd,
                                            float* __restrict__ out,
                                            int B, int F) {
    const int tiles_x = WID / 8;               // 28
    const int tiles_per_batch = tiles_x * (HGT / 8); // 784
    int b = blockIdx.x / tiles_per_batch;
    int tile = blockIdx.x - b * tiles_per_batch;
    int ty = tile / tiles_x;
    int tx = tile - ty * tiles_x;

    int t = threadIdx.x & 63;
    int w = threadIdx.x >> 6;
    int lx = t & 7, ly = t >> 3;
    int x = tx * 8 + lx;
    int y = ty * 8 + ly;
    float px = (2.0f * (float)x + 1.0f) / (float)WID - 1.0f;
    float py = 1.0f - (2.0f * (float)y + 1.0f) / (float)HGT;

    // wave-uniform tile bounds (+ margin)
    float txlo = (2.0f * (float)(tx * 8) + 1.0f) / (float)WID - 1.0f - MARGIN;
    float txhi = (2.0f * (float)(tx * 8 + 7) + 1.0f) / (float)WID - 1.0f + MARGIN;
    float tyhi = 1.0f - (2.0f * (float)(ty * 8) + 1.0f) / (float)HGT + MARGIN;
    float tylo = 1.0f - (2.0f * (float)(ty * 8 + 7) + 1.0f) / (float)HGT - MARGIN;

    const float* fb = fd + b * F * FSTRIDE;

    int chunk = (F + 3) >> 2;
    int fbeg = w * chunk;
    int fend = min(fbeg + chunk, F);

    float best = -1e10f;
    int bidx = -1;
    float bl0 = 0.0f, bl1 = 0.0f, bl2 = 0.0f;
    float prod = 1.0f;

    for (int f = fbeg; f < fend; f++) {
        const float* fp = fb + f * FSTRIDE;
        float bxmin = fp[0], bymin = fp[1], bxmax = fp[2], bymax = fp[3];
        // uniform across the wave: face bbox vs tile bbox (+margin)
        if (bxmin <= txhi && bxmax >= txlo && bymin <= tyhi && bymax >= tylo) {
            float x0 = fp[4], y0 = fp[5], x1 = fp[6], y1 = fp[7], x2 = fp[8], y2 = fp[9];
            float dx2 = px - x2, dy2 = py - y2;
            float lam0 = fp[10] * dx2 + fp[11] * dy2;
            float lam1 = fp[12] * dx2 + fp[13] * dy2;
            float lam2 = 1.0f - lam0 - lam1;
            bool inside = (lam0 >= 0.0f) && (lam1 >= 0.0f) && (lam2 >= 0.0f);

            float dA = seg_d2(px, py, x0, y0, fp[27], fp[28], fp[29]);
            float dB = seg_d2(px, py, x1, y1, fp[30], fp[31], fp[32]);
            float dC = seg_d2(px, py, x2, y2, fp[33], fp[34], fp[35]);
            float d2 = inside ? 0.0f : fminf(dA, fminf(dB, dC));

            // pr = exp(-d2/sigma)*(1-1e-7); exp underflow -> pr=0 -> no-op
            float pr = __expf(d2 * (-1.0f / SIGMA)) * (1.0f - 1e-7f);
            prod *= (1.0f - pr);

            if (inside) {
                float zpix = lam0 * fp[14] + lam1 * fp[15] + lam2 * fp[16];
                if (zpix > best) {
                    best = zpix; bidx = f;
                    bl0 = lam0; bl1 = lam1; bl2 = lam2;
                }
            }
        }
    }

    __shared__ float sc[256], sl0[256], sl1[256], sl2[256], sp[256];
    __shared__ int sidx[256];
    sc[threadIdx.x] = best;
    sl0[threadIdx.x] = bl0; sl1[threadIdx.x] = bl1; sl2[threadIdx.x] = bl2;
    sp[threadIdx.x] = prod;
    sidx[threadIdx.x] = bidx;
    __syncthreads();

    if (w == 0) {
        best = -1e10f; bidx = -1;
        bl0 = 0.0f; bl1 = 0.0f; bl2 = 0.0f;
        prod = 1.0f;
        for (int k = 0; k < 4; k++) {
            int j = k * 64 + t;
            prod *= sp[j];
            float v = sc[j];
            if (v > best) {          // ascending chunk order => first-max kept
                best = v; bidx = sidx[j];
                bl0 = sl0[j]; bl1 = sl1[j]; bl2 = sl2[j];
            }
        }

        float r = 0.0f, g = 0.0f, bb = 0.0f;
        if (bidx >= 0) {
            const float* fp = fb + bidx * FSTRIDE;
            r  = bl0 * fp[18] + bl1 * fp[21] + bl2 * fp[24];
            g  = bl0 * fp[19] + bl1 * fp[22] + bl2 * fp[25];
            bb = bl0 * fp[20] + bl1 * fp[23] + bl2 * fp[26];
        }

        int pixidx = b * NPIX + y * WID + x;
        out[pixidx * 3 + 0] = r;
        out[pixidx * 3 + 1] = g;
        out[pixidx * 3 + 2] = bb;
        out[B * NPIX * 3 + pixidx] = 1.0f - prod;
    }
}

extern "C" void kernel_launch(void* const* d_in, const int* in_sizes, int n_in,
                              void* d_out, int out_size, void* d_ws, size_t ws_size,
                              hipStream_t stream) {
    const float* points = (const float*)d_in[0];
    const int*   faces  = (const int*)d_in[1];
    const float* rot    = (const float*)d_in[2];
    const float* pos    = (const float*)d_in[3];
    const float* proj   = (const float*)d_in[4];
    const float* colors = (const float*)d_in[5];
    float* out = (float*)d_out;

    int F = in_sizes[1] / 3;          // 256
    int B = in_sizes[3] / 3;          // 2
    int P = in_sizes[0] / (3 * B);    // 2048

    float* fd = (float*)d_ws;                          // B*F*FSTRIDE floats
    float* out_normal = out + B * NPIX * 3 + B * NPIX; // normal1 slice

    int nf = B * F;
    face_pre<<<(nf + 255) / 256, 256, 0, stream>>>(points, faces, rot, pos, proj,
                                                   colors, fd, out_normal, B, P, F);

    int blocks = B * (NPIX / 64);   // one 8x8 tile per block
    rast<<<blocks, 256, 0, stream>>>(fd, out, B, F);
}

// Round 4
// 82.736 us; speedup vs baseline: 2.2759x; 1.2160x over previous
//
#include <hip/hip_runtime.h>
#include <math.h>

#define HGT 224
#define WID 224
#define NPIX (HGT * WID)
#define SIGMA 0.0003f
#define EPSV 1e-10f
#define FSTRIDE 36   // floats per face record
// margin: beyond sqrt(12.8*SIGMA)=0.062 from the triangle bbox, pr < 2.8e-6;
// dropping such faces changes improb by < 256*2.8e-6 ~ 7e-4 << 2e-2 threshold.
#define MARGIN 0.062f

// Face record layout (floats):
//  0-3 : bxmin, bymin, bxmax, bymax   (backface -> inverted inf bbox = never hit)
//  4-9 : x0,y0,x1,y1,x2,y2            (projected 2D verts)
// 10-13: a00,a01,a10,a11              (barycentric coeffs, pre-divided by denom)
// 14-16: z0,z1,z2                     (camera-space z per vertex)
// 17   : pad
// 18-26: c0r,c0g,c0b, c1r,c1g,c1b, c2r,c2g,c2b
// 27-29: e01x,e01y,inv01              (segment 0->1: edge vec + 1/(|e|^2+eps))
// 30-32: e12x,e12y,inv12
// 33-35: e20x,e20y,inv20

__global__ void face_pre(const float* __restrict__ points,
                         const int* __restrict__ faces,
                         const float* __restrict__ rot,
                         const float* __restrict__ pos,
                         const float* __restrict__ proj,
                         const float* __restrict__ colors,
                         float* __restrict__ fd,
                         float* __restrict__ out_normal,
                         int B, int P, int F) {
    int gid = blockIdx.x * blockDim.x + threadIdx.x;
    if (gid >= B * F) return;
    int b = gid / F;
    int f = gid - b * F;

    const float* Rb = rot + b * 9;
    float posx = pos[b * 3 + 0], posy = pos[b * 3 + 1], posz = pos[b * 3 + 2];
    float pj0 = proj[0], pj1 = proj[1], pj2 = proj[2];

    float pcx[3], pcy[3], pcz[3], qx[3], qy[3], col[9];
    for (int v = 0; v < 3; v++) {
        int i = faces[f * 3 + v];
        float dx = points[(b * P + i) * 3 + 0] - posx;
        float dy = points[(b * P + i) * 3 + 1] - posy;
        float dz = points[(b * P + i) * 3 + 2] - posz;
        pcx[v] = Rb[0] * dx + Rb[1] * dy + Rb[2] * dz;
        pcy[v] = Rb[3] * dx + Rb[4] * dy + Rb[5] * dz;
        pcz[v] = Rb[6] * dx + Rb[7] * dy + Rb[8] * dz;
        float zz = pcz[v] * pj2;
        qx[v] = (pcx[v] * pj0) / zz;
        qy[v] = (pcy[v] * pj1) / zz;
        col[v * 3 + 0] = colors[(b * P + i) * 3 + 0];
        col[v * 3 + 1] = colors[(b * P + i) * 3 + 1];
        col[v * 3 + 2] = colors[(b * P + i) * 3 + 2];
    }

    float ux = pcx[1] - pcx[0], uy = pcy[1] - pcy[0], uz = pcz[1] - pcz[0];
    float vx = pcx[2] - pcx[0], vy = pcy[2] - pcy[0], vz = pcz[2] - pcz[0];
    float nx = uy * vz - uz * vy;
    float ny = uz * vx - ux * vz;
    float nz = ux * vy - uy * vx;
    float ninv = 1.0f / sqrtf(nx * nx + ny * ny + nz * nz + EPSV);
    out_normal[gid * 3 + 0] = nx * ninv;
    out_normal[gid * 3 + 1] = ny * ninv;
    out_normal[gid * 3 + 2] = nz * ninv;

    float x0 = qx[0], y0 = qy[0], x1 = qx[1], y1 = qy[1], x2 = qx[2], y2 = qy[2];
    float denom = (y1 - y2) * (x0 - x2) + (x2 - x1) * (y0 - y2);
    if (fabsf(denom) < EPSV) denom = EPSV;
    float rd = 1.0f / denom;

    float* fp = fd + gid * FSTRIDE;
    bool front = nz > 0.0f;
    // backfaces: inverted bbox at +/-inf -> every tile test fails
    fp[0] = front ? fminf(x0, fminf(x1, x2)) :  1e30f;
    fp[1] = front ? fminf(y0, fminf(y1, y2)) :  1e30f;
    fp[2] = front ? fmaxf(x0, fmaxf(x1, x2)) : -1e30f;
    fp[3] = front ? fmaxf(y0, fmaxf(y1, y2)) : -1e30f;

    fp[4] = x0; fp[5] = y0; fp[6] = x1; fp[7] = y1; fp[8] = x2; fp[9] = y2;
    fp[10] = (y1 - y2) * rd;
    fp[11] = (x2 - x1) * rd;
    fp[12] = (y2 - y0) * rd;
    fp[13] = (x0 - x2) * rd;
    fp[14] = pcz[0]; fp[15] = pcz[1]; fp[16] = pcz[2];
    fp[17] = 0.0f;
    for (int k = 0; k < 9; k++) fp[18 + k] = col[k];

    float e01x = x1 - x0, e01y = y1 - y0;
    float e12x = x2 - x1, e12y = y2 - y1;
    float e20x = x0 - x2, e20y = y0 - y2;
    fp[27] = e01x; fp[28] = e01y; fp[29] = 1.0f / (e01x * e01x + e01y * e01y + EPSV);
    fp[30] = e12x; fp[31] = e12y; fp[32] = 1.0f / (e12x * e12x + e12y * e12y + EPSV);
    fp[33] = e20x; fp[34] = e20y; fp[35] = 1.0f / (e20x * e20x + e20y * e20y + EPSV);
}

__device__ __forceinline__ float seg_d2(float px, float py, float ax, float ay,
                                        float ex, float ey, float inv) {
    float pax = px - ax, pay = py - ay;
    float t = (pax * ex + pay * ey) * inv;
    t = fminf(fmaxf(t, 0.0f), 1.0f);
    float ddx = pax - t * ex;
    float ddy = pay - t * ey;
    return ddx * ddx + ddy * ddy;
}

// 256 threads = 4 waves. Each block covers one 8x8 pixel tile (64 pixels);
// wave w handles face chunk [w*F/4, (w+1)*F/4). Per 64-face group: one
// vectorized bbox pass (lane l tests face base+l) -> 64-bit ballot mask,
// then iterate set bits only (face index stays in SGPR -> scalar loads).
__global__ __launch_bounds__(256) void rast(const float* __restrict__ fd,
                                            float* __restrict__ out,
                                            int B, int F) {
    const int tiles_x = WID / 8;               // 28
    const int tiles_per_batch = tiles_x * (HGT / 8); // 784
    int b = blockIdx.x / tiles_per_batch;
    int tile = blockIdx.x - b * tiles_per_batch;
    int ty = tile / tiles_x;
    int tx = tile - ty * tiles_x;

    int t = threadIdx.x & 63;
    int w = threadIdx.x >> 6;
    int lx = t & 7, ly = t >> 3;
    int x = tx * 8 + lx;
    int y = ty * 8 + ly;
    float px = (2.0f * (float)x + 1.0f) / (float)WID - 1.0f;
    float py = 1.0f - (2.0f * (float)y + 1.0f) / (float)HGT;

    // wave-uniform tile bounds (+ margin)
    float txlo = (2.0f * (float)(tx * 8) + 1.0f) / (float)WID - 1.0f - MARGIN;
    float txhi = (2.0f * (float)(tx * 8 + 7) + 1.0f) / (float)WID - 1.0f + MARGIN;
    float tyhi = 1.0f - (2.0f * (float)(ty * 8) + 1.0f) / (float)HGT + MARGIN;
    float tylo = 1.0f - (2.0f * (float)(ty * 8 + 7) + 1.0f) / (float)HGT - MARGIN;

    const float* fb = fd + b * F * FSTRIDE;

    int chunk = (F + 3) >> 2;
    int fbeg = w * chunk;
    int fend = min(fbeg + chunk, F);

    float best = -1e10f;
    int bidx = -1;
    float bl0 = 0.0f, bl1 = 0.0f, bl2 = 0.0f;
    float prod = 1.0f;
    const float INSIDE_FACTOR = 1.0f - (1.0f - 1e-7f); // == slow path at d2=0

    for (int base = fbeg; base < fend; base += 64) {
        // vectorized bbox pass: lane t tests face base+t
        bool pass = false;
        int fl = base + t;
        if (fl < fend) {
            const float4 bb4 = *(const float4*)(fb + fl * FSTRIDE);
            pass = (bb4.x <= txhi) & (bb4.z >= txlo) & (bb4.y <= tyhi) & (bb4.w >= tylo);
        }
        unsigned long long mask = __ballot(pass);

        while (mask) {
            int fo = (int)__builtin_ctzll(mask);
            mask &= mask - 1;
            int fi = base + fo;                 // SGPR-uniform face index
            const float* fp = fb + fi * FSTRIDE;

            float dx2 = px - fp[8], dy2 = py - fp[9];
            float lam0 = fp[10] * dx2 + fp[11] * dy2;
            float lam1 = fp[12] * dx2 + fp[13] * dy2;
            float lam2 = 1.0f - lam0 - lam1;
            bool inside = (lam0 >= 0.0f) && (lam1 >= 0.0f) && (lam2 >= 0.0f);
            unsigned long long ins = __ballot(inside);

            if (ins) {  // wave-uniform: someone is inside -> z/argmax
                float zpix = lam0 * fp[14] + lam1 * fp[15] + lam2 * fp[16];
                if (inside && zpix > best) {
                    best = zpix; bidx = fi;
                    bl0 = lam0; bl1 = lam1; bl2 = lam2;
                }
            }

            if (ins == ~0ULL) {
                // whole wave inside: d2=0 for all lanes, constant factor
                prod *= INSIDE_FACTOR;
            } else {
                float dA = seg_d2(px, py, fp[4], fp[5], fp[27], fp[28], fp[29]);
                float dB = seg_d2(px, py, fp[6], fp[7], fp[30], fp[31], fp[32]);
                float dC = seg_d2(px, py, fp[8], fp[9], fp[33], fp[34], fp[35]);
                float d2 = inside ? 0.0f : fminf(dA, fminf(dB, dC));
                // pr = exp(-d2/sigma)*(1-1e-7); exp underflow -> pr=0 -> no-op
                float pr = __expf(d2 * (-1.0f / SIGMA)) * (1.0f - 1e-7f);
                prod *= (1.0f - pr);
            }
        }
    }

    __shared__ float sc[256], sl0[256], sl1[256], sl2[256], sp[256];
    __shared__ int sidx[256];
    sc[threadIdx.x] = best;
    sl0[threadIdx.x] = bl0; sl1[threadIdx.x] = bl1; sl2[threadIdx.x] = bl2;
    sp[threadIdx.x] = prod;
    sidx[threadIdx.x] = bidx;
    __syncthreads();

    if (w == 0) {
        best = -1e10f; bidx = -1;
        bl0 = 0.0f; bl1 = 0.0f; bl2 = 0.0f;
        prod = 1.0f;
        for (int k = 0; k < 4; k++) {
            int j = k * 64 + t;
            prod *= sp[j];
            float v = sc[j];
            if (v > best) {          // ascending chunk order => first-max kept
                best = v; bidx = sidx[j];
                bl0 = sl0[j]; bl1 = sl1[j]; bl2 = sl2[j];
            }
        }

        float r = 0.0f, g = 0.0f, bb = 0.0f;
        if (bidx >= 0) {
            const float* fp = fb + bidx * FSTRIDE;
            r  = bl0 * fp[18] + bl1 * fp[21] + bl2 * fp[24];
            g  = bl0 * fp[19] + bl1 * fp[22] + bl2 * fp[25];
            bb = bl0 * fp[20] + bl1 * fp[23] + bl2 * fp[26];
        }

        int pixidx = b * NPIX + y * WID + x;
        out[pixidx * 3 + 0] = r;
        out[pixidx * 3 + 1] = g;
        out[pixidx * 3 + 2] = bb;
        out[B * NPIX * 3 + pixidx] = 1.0f - prod;
    }
}

extern "C" void kernel_launch(void* const* d_in, const int* in_sizes, int n_in,
                              void* d_out, int out_size, void* d_ws, size_t ws_size,
                              hipStream_t stream) {
    const float* points = (const float*)d_in[0];
    const int*   faces  = (const int*)d_in[1];
    const float* rot    = (const float*)d_in[2];
    const float* pos    = (const float*)d_in[3];
    const float* proj   = (const float*)d_in[4];
    const float* colors = (const float*)d_in[5];
    float* out = (float*)d_out;

    int F = in_sizes[1] / 3;          // 256
    int B = in_sizes[3] / 3;          // 2
    int P = in_sizes[0] / (3 * B);    // 2048

    float* fd = (float*)d_ws;                          // B*F*FSTRIDE floats
    float* out_normal = out + B * NPIX * 3 + B * NPIX; // normal1 slice

    int nf = B * F;
    face_pre<<<(nf + 255) / 256, 256, 0, stream>>>(points, faces, rot, pos, proj,
                                                   colors, fd, out_normal, B, P, F);

    int blocks = B * (NPIX / 64);   // one 8x8 tile per block
    rast<<<blocks, 256, 0, stream>>>(fd, out, B, F);
}

// Round 5
// 80.975 us; speedup vs baseline: 2.3254x; 1.0217x over previous
//
#include <hip/hip_runtime.h>
#include <math.h>

#define HGT 224
#define WID 224
#define NPIX (HGT * WID)
#define SIGMA 0.0003f
#define EPSV 1e-10f
#define FILT_STRIDE 16   // floats per face filter record
#define DATA_STRIDE 32   // floats per face data record
// margin: beyond sqrt(12.8*SIGMA)=0.062 from the triangle, pr < 2.8e-6;
// dropping such faces changes improb by < 256*2.8e-6 ~ 7e-4 << 2e-2 threshold.
#define MARGIN 0.062f
// 8x8 tile: pixel centers span +/-3.5 pixels from tile center; pitch 2/224
#define HALFDIAG 0.04420f
#define BAND (MARGIN + HALFDIAG)

// Filter record (floats, coalesced float4 reads in vectorized prefilter):
//  0-3 : bxmin, bymin, bxmax, bymax   (backface -> inverted inf bbox)
//  4-6 : D0x, D0y, D0c                (signed-dist to edge-line 0: D.x*px+D.y*py+D.c, >0 inside)
//  7-9 : D1x, D1y, D1c
// 10-12: D2x, D2y, D2c
// 13-15: pad
//
// Data record (floats, scalar reads in heavy loop):
//  0-5 : x0,y0,x1,y1,x2,y2            (projected 2D verts)
//  6-9 : a00,a01,a10,a11              (barycentric coeffs, pre-divided by denom)
// 10-12: z0,z1,z2                     (camera-space z per vertex)
// 13   : pad
// 14-22: c0r,c0g,c0b, c1r,c1g,c1b, c2r,c2g,c2b
// 23-25: e01x,e01y,inv01              (segment 0->1: edge vec + 1/(|e|^2+eps))
// 26-28: e12x,e12y,inv12
// 29-31: e20x,e20y,inv20

__global__ void face_pre(const float* __restrict__ points,
                         const int* __restrict__ faces,
                         const float* __restrict__ rot,
                         const float* __restrict__ pos,
                         const float* __restrict__ proj,
                         const float* __restrict__ colors,
                         float* __restrict__ filt,
                         float* __restrict__ data,
                         float* __restrict__ out_normal,
                         int B, int P, int F) {
    int gid = blockIdx.x * blockDim.x + threadIdx.x;
    if (gid >= B * F) return;
    int b = gid / F;
    int f = gid - b * F;

    const float* Rb = rot + b * 9;
    float posx = pos[b * 3 + 0], posy = pos[b * 3 + 1], posz = pos[b * 3 + 2];
    float pj0 = proj[0], pj1 = proj[1], pj2 = proj[2];

    float pcx[3], pcy[3], pcz[3], qx[3], qy[3], col[9];
    for (int v = 0; v < 3; v++) {
        int i = faces[f * 3 + v];
        float dx = points[(b * P + i) * 3 + 0] - posx;
        float dy = points[(b * P + i) * 3 + 1] - posy;
        float dz = points[(b * P + i) * 3 + 2] - posz;
        pcx[v] = Rb[0] * dx + Rb[1] * dy + Rb[2] * dz;
        pcy[v] = Rb[3] * dx + Rb[4] * dy + Rb[5] * dz;
        pcz[v] = Rb[6] * dx + Rb[7] * dy + Rb[8] * dz;
        float zz = pcz[v] * pj2;
        qx[v] = (pcx[v] * pj0) / zz;
        qy[v] = (pcy[v] * pj1) / zz;
        col[v * 3 + 0] = colors[(b * P + i) * 3 + 0];
        col[v * 3 + 1] = colors[(b * P + i) * 3 + 1];
        col[v * 3 + 2] = colors[(b * P + i) * 3 + 2];
    }

    float ux = pcx[1] - pcx[0], uy = pcy[1] - pcy[0], uz = pcz[1] - pcz[0];
    float vx = pcx[2] - pcx[0], vy = pcy[2] - pcy[0], vz = pcz[2] - pcz[0];
    float nx = uy * vz - uz * vy;
    float ny = uz * vx - ux * vz;
    float nz = ux * vy - uy * vx;
    float ninv = 1.0f / sqrtf(nx * nx + ny * ny + nz * nz + EPSV);
    out_normal[gid * 3 + 0] = nx * ninv;
    out_normal[gid * 3 + 1] = ny * ninv;
    out_normal[gid * 3 + 2] = nz * ninv;

    float x0 = qx[0], y0 = qy[0], x1 = qx[1], y1 = qy[1], x2 = qx[2], y2 = qy[2];
    float denom = (y1 - y2) * (x0 - x2) + (x2 - x1) * (y0 - y2);
    if (fabsf(denom) < EPSV) denom = EPSV;
    float rd = 1.0f / denom;

    float a00 = (y1 - y2) * rd;
    float a01 = (x2 - x1) * rd;
    float a10 = (y2 - y0) * rd;
    float a11 = (x0 - x2) * rd;

    // ---- filter record ----
    float* fq = filt + gid * FILT_STRIDE;
    bool front = nz > 0.0f;
    fq[0] = front ? fminf(x0, fminf(x1, x2)) :  1e30f;
    fq[1] = front ? fminf(y0, fminf(y1, y2)) :  1e30f;
    fq[2] = front ? fmaxf(x0, fmaxf(x1, x2)) : -1e30f;
    fq[3] = front ? fmaxf(y0, fmaxf(y1, y2)) : -1e30f;

    // lam0(p) = a00*px + a01*py - (a00*x2 + a01*y2)    (grad g0 = (a00,a01))
    // lam1(p) = a10*px + a11*py - (a10*x2 + a11*y2)
    // lam2(p) = g2x*px + g2y*py + (1 - g2x*x2 - g2y*y2), g2 = -(g0+g1)
    // signed Euclidean dist to edge-line i = lam_i / |g_i|  (>0 inside)
    // degenerate faces: g ~ 0 -> D terms ~ 0 -> dist 0 -> never rejected (safe)
    float n0 = 1.0f / sqrtf(a00 * a00 + a01 * a01 + EPSV);
    float n1 = 1.0f / sqrtf(a10 * a10 + a11 * a11 + EPSV);
    float g2x = -(a00 + a10), g2y = -(a01 + a11);
    float n2 = 1.0f / sqrtf(g2x * g2x + g2y * g2y + EPSV);
    fq[4] = a00 * n0;
    fq[5] = a01 * n0;
    fq[6] = -(a00 * x2 + a01 * y2) * n0;
    fq[7] = a10 * n1;
    fq[8] = a11 * n1;
    fq[9] = -(a10 * x2 + a11 * y2) * n1;
    fq[10] = g2x * n2;
    fq[11] = g2y * n2;
    fq[12] = (1.0f - g2x * x2 - g2y * y2) * n2;
    fq[13] = 0.0f; fq[14] = 0.0f; fq[15] = 0.0f;

    // ---- data record ----
    float* fp = data + gid * DATA_STRIDE;
    fp[0] = x0; fp[1] = y0; fp[2] = x1; fp[3] = y1; fp[4] = x2; fp[5] = y2;
    fp[6] = a00; fp[7] = a01; fp[8] = a10; fp[9] = a11;
    fp[10] = pcz[0]; fp[11] = pcz[1]; fp[12] = pcz[2];
    fp[13] = 0.0f;
    for (int k = 0; k < 9; k++) fp[14 + k] = col[k];

    float e01x = x1 - x0, e01y = y1 - y0;
    float e12x = x2 - x1, e12y = y2 - y1;
    float e20x = x0 - x2, e20y = y0 - y2;
    fp[23] = e01x; fp[24] = e01y; fp[25] = 1.0f / (e01x * e01x + e01y * e01y + EPSV);
    fp[26] = e12x; fp[27] = e12y; fp[28] = 1.0f / (e12x * e12x + e12y * e12y + EPSV);
    fp[29] = e20x; fp[30] = e20y; fp[31] = 1.0f / (e20x * e20x + e20y * e20y + EPSV);
}

__device__ __forceinline__ float seg_d2(float px, float py, float ax, float ay,
                                        float ex, float ey, float inv) {
    float pax = px - ax, pay = py - ay;
    float t = (pax * ex + pay * ey) * inv;
    t = fminf(fmaxf(t, 0.0f), 1.0f);
    float ddx = pax - t * ex;
    float ddy = pay - t * ey;
    return ddx * ddx + ddy * ddy;
}

// 256 threads = 4 waves, one 8x8 pixel tile per block; wave w handles faces
// [w*64, w*64+64). Prefilter: lane l tests face base+l with bbox AND
// 3-edge-line signed distance at the tile center (conservative: inside
// pixels never dropped; dropped faces contribute pr < 2.8e-6). Ballot ->
// iterate surviving faces only, face index in SGPR -> scalar data loads.
__global__ __launch_bounds__(256) void rast(const float* __restrict__ filt,
                                            const float* __restrict__ data,
                                            float* __restrict__ out,
                                            int B, int F) {
    const int tiles_x = WID / 8;               // 28
    const int tiles_per_batch = tiles_x * (HGT / 8); // 784
    int b = blockIdx.x / tiles_per_batch;
    int tile = blockIdx.x - b * tiles_per_batch;
    int ty = tile / tiles_x;
    int tx = tile - ty * tiles_x;

    int t = threadIdx.x & 63;
    int w = threadIdx.x >> 6;
    int lx = t & 7, ly = t >> 3;
    int x = tx * 8 + lx;
    int y = ty * 8 + ly;
    float px = (2.0f * (float)x + 1.0f) / (float)WID - 1.0f;
    float py = 1.0f - (2.0f * (float)y + 1.0f) / (float)HGT;

    // wave-uniform tile bounds (+ margin) and tile center
    float txlo = (2.0f * (float)(tx * 8) + 1.0f) / (float)WID - 1.0f - MARGIN;
    float txhi = (2.0f * (float)(tx * 8 + 7) + 1.0f) / (float)WID - 1.0f + MARGIN;
    float tyhi = 1.0f - (2.0f * (float)(ty * 8) + 1.0f) / (float)HGT + MARGIN;
    float tylo = 1.0f - (2.0f * (float)(ty * 8 + 7) + 1.0f) / (float)HGT - MARGIN;
    float cx = (16.0f * (float)tx + 8.0f) / (float)WID - 1.0f;
    float cy = 1.0f - (16.0f * (float)ty + 8.0f) / (float)HGT;

    const float* fltb = filt + (size_t)b * F * FILT_STRIDE;
    const float* datb = data + (size_t)b * F * DATA_STRIDE;

    int chunk = (F + 3) >> 2;
    int fbeg = w * chunk;
    int fend = min(fbeg + chunk, F);

    float best = -1e10f;
    int bidx = -1;
    float bl0 = 0.0f, bl1 = 0.0f, bl2 = 0.0f;
    float prod = 1.0f;
    const float INSIDE_FACTOR = 1.0f - (1.0f - 1e-7f); // == slow path at d2=0

    for (int base = fbeg; base < fend; base += 64) {
        // vectorized prefilter: lane t tests face base+t
        bool pass = false;
        int fl = base + t;
        if (fl < fend) {
            const float* fq = fltb + fl * FILT_STRIDE;
            float4 bb = *(const float4*)fq;
            float4 e0 = *(const float4*)(fq + 4);   // D0x,D0y,D0c,D1x
            float4 e1 = *(const float4*)(fq + 8);   // D1y,D1c,D2x,D2y
            float  dc2 = fq[12];                    // D2c
            bool bpass = (bb.x <= txhi) & (bb.z >= txlo) & (bb.y <= tyhi) & (bb.w >= tylo);
            float d0 = e0.x * cx + e0.y * cy + e0.z;
            float d1 = e0.w * cx + e1.x * cy + e1.y;
            float d2 = e1.z * cx + e1.w * cy + dc2;
            pass = bpass & (fminf(d0, fminf(d1, d2)) >= -BAND);
        }
        unsigned long long mask = __ballot(pass);

        while (mask) {
            int fo = (int)__builtin_ctzll(mask);
            mask &= mask - 1;
            int fi = base + fo;                 // SGPR-uniform face index
            const float* fp = datb + fi * DATA_STRIDE;

            float dx2 = px - fp[4], dy2 = py - fp[5];
            float lam0 = fp[6] * dx2 + fp[7] * dy2;
            float lam1 = fp[8] * dx2 + fp[9] * dy2;
            float lam2 = 1.0f - lam0 - lam1;
            bool inside = (lam0 >= 0.0f) && (lam1 >= 0.0f) && (lam2 >= 0.0f);
            unsigned long long ins = __ballot(inside);

            if (ins) {  // wave-uniform: someone inside -> z/argmax
                float zpix = lam0 * fp[10] + lam1 * fp[11] + lam2 * fp[12];
                if (inside && zpix > best) {
                    best = zpix; bidx = fi;
                    bl0 = lam0; bl1 = lam1; bl2 = lam2;
                }
            }

            if (ins == ~0ULL) {
                // whole wave inside: d2=0 for all lanes, constant factor
                prod *= INSIDE_FACTOR;
            } else {
                float dA = seg_d2(px, py, fp[0], fp[1], fp[23], fp[24], fp[25]);
                float dB = seg_d2(px, py, fp[2], fp[3], fp[26], fp[27], fp[28]);
                float dC = seg_d2(px, py, fp[4], fp[5], fp[29], fp[30], fp[31]);
                float d2 = inside ? 0.0f : fminf(dA, fminf(dB, dC));
                // pr = exp(-d2/sigma)*(1-1e-7); exp underflow -> pr=0 -> no-op
                float pr = __expf(d2 * (-1.0f / SIGMA)) * (1.0f - 1e-7f);
                prod *= (1.0f - pr);
            }
        }
    }

    __shared__ float sc[256], sl0[256], sl1[256], sl2[256], sp[256];
    __shared__ int sidx[256];
    sc[threadIdx.x] = best;
    sl0[threadIdx.x] = bl0; sl1[threadIdx.x] = bl1; sl2[threadIdx.x] = bl2;
    sp[threadIdx.x] = prod;
    sidx[threadIdx.x] = bidx;
    __syncthreads();

    if (w == 0) {
        best = -1e10f; bidx = -1;
        bl0 = 0.0f; bl1 = 0.0f; bl2 = 0.0f;
        prod = 1.0f;
        for (int k = 0; k < 4; k++) {
            int j = k * 64 + t;
            prod *= sp[j];
            float v = sc[j];
            if (v > best) {          // ascending chunk order => first-max kept
                best = v; bidx = sidx[j];
                bl0 = sl0[j]; bl1 = sl1[j]; bl2 = sl2[j];
            }
        }

        float r = 0.0f, g = 0.0f, bb = 0.0f;
        if (bidx >= 0) {
            const float* fp = datb + bidx * DATA_STRIDE;
            r  = bl0 * fp[14] + bl1 * fp[17] + bl2 * fp[20];
            g  = bl0 * fp[15] + bl1 * fp[18] + bl2 * fp[21];
            bb = bl0 * fp[16] + bl1 * fp[19] + bl2 * fp[22];
        }

        int pixidx = b * NPIX + y * WID + x;
        out[pixidx * 3 + 0] = r;
        out[pixidx * 3 + 1] = g;
        out[pixidx * 3 + 2] = bb;
        out[B * NPIX * 3 + pixidx] = 1.0f - prod;
    }
}

extern "C" void kernel_launch(void* const* d_in, const int* in_sizes, int n_in,
                              void* d_out, int out_size, void* d_ws, size_t ws_size,
                              hipStream_t stream) {
    const float* points = (const float*)d_in[0];
    const int*   faces  = (const int*)d_in[1];
    const float* rot    = (const float*)d_in[2];
    const float* pos    = (const float*)d_in[3];
    const float* proj   = (const float*)d_in[4];
    const float* colors = (const float*)d_in[5];
    float* out = (float*)d_out;

    int F = in_sizes[1] / 3;          // 256
    int B = in_sizes[3] / 3;          // 2
    int P = in_sizes[0] / (3 * B);    // 2048

    float* filt = (float*)d_ws;                        // B*F*16 floats
    float* data = filt + (size_t)B * F * FILT_STRIDE;  // B*F*32 floats
    float* out_normal = out + B * NPIX * 3 + B * NPIX; // normal1 slice

    int nf = B * F;
    face_pre<<<(nf + 255) / 256, 256, 0, stream>>>(points, faces, rot, pos, proj,
                                                   colors, filt, data, out_normal,
                                                   B, P, F);

    int blocks = B * (NPIX / 64);   // one 8x8 tile per block
    rast<<<blocks, 256, 0, stream>>>(filt, data, out, B, F);
}